// Round 6
// baseline (1142.949 us; speedup 1.0000x reference)
//
#include <hip/hip_runtime.h>

// PolicyNetGARCH: B=1024 S=512 OBS=5 NINS=2 H=32 NBLK=4
// Round 6: 2 waves per WG, one WG per batch element.
//   wave 0 = input proj + LSTM blocks 0,1 ; wave 1 = blocks 2,3 + head.
// 2 blocks/wave -> 128 weight VGPRs (f16 pairs) + working set fits the
// 256-VGPR arch file (round 5's 4-block version overflowed into AGPRs and
// paid v_accvgpr traffic on every dot operand).
// Super-tick = 2 timesteps per barrier; xt pairs handed wave0->wave1 via a
// parity-double-buffered 512B LDS slot. Gates pre-scaled by log2e (2*log2e
// for tanh rows) so activations are raw v_exp_f32. Cross-lane: DPP reduce,
// quad_perm pack, permlane32_swap, readlane->SGPR broadcast.

constexpr int B_ = 1024, S_ = 512, OBS_ = 5, NINS_ = 2, H_ = 32, NBLK_ = 4;
constexpr int TT_ = S_ / 2;   // super-ticks
constexpr float EPS_ = 1e-6f;
constexpr float LOG2E_ = 1.4426950408889634f;

typedef __fp16 half2_t __attribute__((ext_vector_type(2)));

__device__ __forceinline__ float rcp_(float x) { return __builtin_amdgcn_rcpf(x); }
__device__ __forceinline__ float rsq_(float x) { return __builtin_amdgcn_rsqf(x); }
__device__ __forceinline__ float ex2_(float x) { return __builtin_amdgcn_exp2f(x); }

__device__ __forceinline__ float dot2_(half2_t a, half2_t b, float c) {
  return __builtin_amdgcn_fdot2(a, b, c, false);
}
__device__ __forceinline__ half2_t pk_(float a, float b) {
  return __builtin_amdgcn_cvt_pkrtz(a, b);
}

template <int CTRL>
__device__ __forceinline__ float dppadd_(float v) {
  int m = __builtin_amdgcn_update_dpp(0, __builtin_bit_cast(int, v),
                                      CTRL, 0xF, 0xF, true);
  return v + __builtin_bit_cast(float, m);
}

// Sum over lanes 0..31 (low half), SGPR-broadcast to all lanes.
__device__ __forceinline__ float half_reduce_bcast_(float v) {
  v = dppadd_<0x111>(v);  // row_shr:1
  v = dppadd_<0x112>(v);  // row_shr:2
  v = dppadd_<0x114>(v);  // row_shr:4
  v = dppadd_<0x118>(v);  // row_shr:8
  v = dppadd_<0x142>(v);  // row_bcast:15 -> lane31 = sum(0..31)
  int s = __builtin_amdgcn_readlane(__builtin_bit_cast(int, v), 31);
  return __builtin_bit_cast(float, s);
}

__device__ __forceinline__ float rinv_of_(float xt) {
  const float ms = half_reduce_bcast_(xt * xt);
  return rsq_(ms * (1.0f / 32.0f) + EPS_);
}

// Value held by lane^32, valid in LOW lanes.
__device__ __forceinline__ float swap32_low_(float v) {
#if __has_builtin(__builtin_amdgcn_permlane32_swap)
  auto r = __builtin_amdgcn_permlane32_swap(
      __builtin_bit_cast(int, v), __builtin_bit_cast(int, v), false, false);
  return __builtin_bit_cast(float, (int)r[1]);
#else
  return __shfl_xor(v, 32);
#endif
}

// quad_perm(1,0,3,2): lane^1 exchange.
__device__ __forceinline__ float pairswap_(float v) {
  int m = __builtin_amdgcn_update_dpp(0, __builtin_bit_cast(int, v),
                                      0xB1, 0xF, 0xF, true);
  return __builtin_bit_cast(float, m);
}

// pack low-half 32-vector into 16 SGPR f16-pairs (broadcast)
__device__ __forceinline__ void bcast16_(float y, int (&s)[16]) {
  const half2_t p = pk_(y, pairswap_(y));  // valid at even low lanes
  const int pi = __builtin_bit_cast(int, p);
#pragma unroll
  for (int u = 0; u < 16; ++u) s[u] = __builtin_amdgcn_readlane(pi, 2 * u);
}

// One LSTM block step. xt valid in low lanes (mirrored ok); returns h_new
// (valid in low lanes); updates cc and the SGPR-packed h state.
__device__ __forceinline__ float lstm_block_(
    float xt, const half2_t (&w0)[32], const half2_t (&w1)[32],
    float bias0, float bias1, float rw,
    float& cc, int (&s_h)[16], float aC, float dC) {
  int s_x[16];
  bcast16_(xt * rw, s_x);
  const float rinv = rinv_of_(xt);   // off the broadcast critical path

  float a0x = 0.f, a1x = 0.f, a0xb = 0.f, a1xb = 0.f;
#pragma unroll
  for (int u = 0; u < 16; u += 2) {
    half2_t h0 = __builtin_bit_cast(half2_t, s_x[u]);
    half2_t h1 = __builtin_bit_cast(half2_t, s_x[u + 1]);
    a0x  = dot2_(h0, w0[u],     a0x);
    a1x  = dot2_(h0, w1[u],     a1x);
    a0xb = dot2_(h1, w0[u + 1], a0xb);
    a1xb = dot2_(h1, w1[u + 1], a1xb);
  }
  float a0h = bias0, a1h = bias1, a0hb = 0.f, a1hb = 0.f;
#pragma unroll
  for (int u = 0; u < 16; u += 2) {
    half2_t h0 = __builtin_bit_cast(half2_t, s_h[u]);
    half2_t h1 = __builtin_bit_cast(half2_t, s_h[u + 1]);
    a0h  = dot2_(h0, w0[16 + u], a0h);
    a1h  = dot2_(h0, w1[16 + u], a1h);
    a0hb = dot2_(h1, w0[17 + u], a0hb);
    a1hb = dot2_(h1, w1[17 + u], a1hb);
  }
  const float a0 = fmaf(rinv, a0x + a0xb, a0h + a0hb);  // log2e-scaled gates
  const float a1 = fmaf(rinv, a1x + a1xb, a1h + a1hb);

  // low lane: a0=i, a1=g ; high lane: a0=f, a1=o   (exp2 domain)
  const float g0 = rcp_(1.0f + ex2_(-a0));
  const float g1 = fmaf(aC, rcp_(1.0f + ex2_(-a1)), dC);
  const float x0 = swap32_low_(g0);  // low: sig(f)
  const float x1 = swap32_low_(g1);  // low: sig(o)
  cc = x0 * cc + g0 * g1;
  const float tc = fmaf(2.f, rcp_(1.0f + ex2_(-2.f * LOG2E_ * cc)), -1.f);
  const float hn = x1 * tc;
  bcast16_(hn, s_h);
  return hn;
}

__global__ __launch_bounds__(128, 1) void garch_dual_kernel(
    const float* __restrict__ obs, const float* __restrict__ prev,
    const float* __restrict__ W_in, const float* __restrict__ b_in,
    const float* __restrict__ rms_w,
    const float* __restrict__ W_ih, const float* __restrict__ W_hh,
    const float* __restrict__ b_ih, const float* __restrict__ b_hh,
    const float* __restrict__ head_w, const float* __restrict__ head_b,
    float* __restrict__ out) {
  const int b    = blockIdx.x;
  const int w    = threadIdx.x >> 6;   // wave role: 0 = blocks 0,1 ; 1 = 2,3+head
  const int lane = threadIdx.x & 63;
  const int hl   = lane & 31;
  const bool low = (lane < 32);

  __shared__ float slot[2][2][H_];     // [parity][step][h]

  const float aC = low ?  2.f : 1.f;
  const float dC = low ? -1.f : 0.f;
  const float s1 = low ? 2.f * LOG2E_ : LOG2E_;

  // ---- weights for this wave's 2 blocks ----
  half2_t w0[2][32], w1[2][32];
  float bias0[2], bias1[2], rwv[2];
#pragma unroll
  for (int k = 0; k < 2; ++k) {
    const int kg = 2 * w + k;
    const float2* Wih0 = (const float2*)(W_ih + (size_t)kg * 128 * 32 + (size_t)lane * 32);
    const float2* Wih1 = (const float2*)(W_ih + (size_t)kg * 128 * 32 + (size_t)(lane + 64) * 32);
    const float2* Whh0 = (const float2*)(W_hh + (size_t)kg * 128 * 32 + (size_t)lane * 32);
    const float2* Whh1 = (const float2*)(W_hh + (size_t)kg * 128 * 32 + (size_t)(lane + 64) * 32);
#pragma unroll
    for (int t = 0; t < 16; ++t) {
      float2 a = Wih0[t], c2 = Whh0[t], d2 = Wih1[t], e2 = Whh1[t];
      w0[k][t]      = pk_(a.x * LOG2E_,  a.y * LOG2E_);
      w0[k][16 + t] = pk_(c2.x * LOG2E_, c2.y * LOG2E_);
      w1[k][t]      = pk_(d2.x * s1,     d2.y * s1);
      w1[k][16 + t] = pk_(e2.x * s1,     e2.y * s1);
    }
    bias0[k] = (b_ih[kg * 128 + lane]      + b_hh[kg * 128 + lane])      * LOG2E_;
    bias1[k] = (b_ih[kg * 128 + lane + 64] + b_hh[kg * 128 + lane + 64]) * s1;
    rwv[k]   = rms_w[kg * 32 + hl];
  }

  // wave-role-specific constants
  float win[7]; float bi = 0.f;
  float hw0 = 0.f, hw1 = 0.f, hb0 = 0.f, hb1 = 0.f;
  if (w == 0) {
#pragma unroll
    for (int j = 0; j < 7; ++j) win[j] = W_in[hl * 7 + j];
    bi = b_in[hl];
  } else {
    hw0 = head_w[hl]      * LOG2E_;
    hw1 = head_w[32 + hl] * LOG2E_;
    hb0 = head_b[0] * LOG2E_;
    hb1 = head_b[1] * LOG2E_;
  }

  float cc[2] = {0.f, 0.f};
  int s_h[2][16];
#pragma unroll
  for (int k = 0; k < 2; ++k)
#pragma unroll
    for (int u = 0; u < 16; ++u) s_h[k][u] = 0;

  const float* obs_b  = obs  + (size_t)b * S_ * OBS_;
  const float* prev_b = prev + (size_t)b * S_ * NINS_;
  float incur[14], innx[14];   // timestep pair inputs (A: 0..6, B: 7..13)
  if (w == 0) {
#pragma unroll
    for (int j = 0; j < 5; ++j) { incur[j] = obs_b[j]; incur[7 + j] = obs_b[5 + j]; }
    incur[5]  = prev_b[0]; incur[6]  = prev_b[1];
    incur[12] = prev_b[2]; incur[13] = prev_b[3];
  }

  float* out_y  = out;                                   // [2][B][S]
  float* out_hT = out + (size_t)NINS_ * B_ * S_;         // [4][B][H]
  float* out_cT = out_hT + (size_t)NBLK_ * B_ * H_;      // [4][B][H]

  for (int tau = 0; tau <= TT_; ++tau) {
    __syncthreads();
    if (w == 0) {
      if (tau >= TT_) continue;
      const int t0 = 2 * tau;
      // xt for both timesteps from prefetched inputs
      float xtA = bi, xtB = bi;
#pragma unroll
      for (int j = 0; j < 7; ++j) {
        xtA = fmaf(win[j], incur[j],     xtA);
        xtB = fmaf(win[j], incur[7 + j], xtB);
      }
      if (tau + 1 < TT_) {   // prefetch next pair (off-chain)
        const float* o2 = obs_b  + (size_t)(t0 + 2) * OBS_;
        const float* p2 = prev_b + (size_t)(t0 + 2) * NINS_;
#pragma unroll
        for (int j = 0; j < 5; ++j) { innx[j] = o2[j]; innx[7 + j] = o2[5 + j]; }
        innx[5]  = p2[0]; innx[6]  = p2[1];
        innx[12] = p2[2]; innx[13] = p2[3];
      }
      // timestep A through blocks 0,1
      xtA += lstm_block_(xtA, w0[0], w1[0], bias0[0], bias1[0], rwv[0], cc[0], s_h[0], aC, dC);
      xtA += lstm_block_(xtA, w0[1], w1[1], bias0[1], bias1[1], rwv[1], cc[1], s_h[1], aC, dC);
      // timestep B through blocks 0,1
      xtB += lstm_block_(xtB, w0[0], w1[0], bias0[0], bias1[0], rwv[0], cc[0], s_h[0], aC, dC);
      float hB1 = lstm_block_(xtB, w0[1], w1[1], bias0[1], bias1[1], rwv[1], cc[1], s_h[1], aC, dC);
      xtB += hB1;
      if (low) {
        slot[tau & 1][0][hl] = xtA;
        slot[tau & 1][1][hl] = xtB;
      }
      if (tau == TT_ - 1 && low) {
        // h_new of block1 at t=S-1 is hB1 ; block0's h is in s_h[0] (repack from xt chain is gone),
        // so recover block0 h from its SGPR-packed state.
        const int ph0 = s_h[0][hl >> 1];
        const half2_t h0v = __builtin_bit_cast(half2_t, ph0);
        out_hT[((size_t)0 * B_ + b) * H_ + hl] = (float)h0v[hl & 1] * 0.f +  // placeholder never taken
                                                 (float)h0v[hl & 1];
        out_hT[((size_t)1 * B_ + b) * H_ + hl] = hB1;
        out_cT[((size_t)0 * B_ + b) * H_ + hl] = cc[0];
        out_cT[((size_t)1 * B_ + b) * H_ + hl] = cc[1];
      }
#pragma unroll
      for (int j = 0; j < 14; ++j) incur[j] = innx[j];
    } else {
      if (tau < 1) continue;
      const int tt = tau - 1;
      const int t0 = 2 * tt;
      const int rp = (tau + 1) & 1;   // parity written by wave 0 at tau-1
      float xtA = slot[rp][0][hl];
      float xtB = slot[rp][1][hl];
      // timestep A through blocks 2,3 + head
      xtA += lstm_block_(xtA, w0[0], w1[0], bias0[0], bias1[0], rwv[0], cc[0], s_h[0], aC, dC);
      float hA3 = lstm_block_(xtA, w0[1], w1[1], bias0[1], bias1[1], rwv[1], cc[1], s_h[1], aC, dC);
      xtA += hA3;
      const float p0A = half_reduce_bcast_(xtA * hw0) + hb0;
      const float p1A = half_reduce_bcast_(xtA * hw1) + hb1;
      // timestep B
      xtB += lstm_block_(xtB, w0[0], w1[0], bias0[0], bias1[0], rwv[0], cc[0], s_h[0], aC, dC);
      float hB3 = lstm_block_(xtB, w0[1], w1[1], bias0[1], bias1[1], rwv[1], cc[1], s_h[1], aC, dC);
      xtB += hB3;
      const float p0B = half_reduce_bcast_(xtB * hw0) + hb0;
      const float p1B = half_reduce_bcast_(xtB * hw1) + hb1;
      if (lane == 0) {
        const float v0A = copysignf(fminf(ex2_(fabsf(p0A)) - 1.0f, 5.0f),  p0A);
        const float v0B = copysignf(fminf(ex2_(fabsf(p0B)) - 1.0f, 5.0f),  p0B);
        const float v1A = copysignf(fminf(ex2_(fabsf(p1A)) - 1.0f, 10.0f), p1A);
        const float v1B = copysignf(fminf(ex2_(fabsf(p1B)) - 1.0f, 10.0f), p1B);
        *(float2*)&out_y[(size_t)b * S_ + t0]                   = make_float2(v0A, v0B);
        *(float2*)&out_y[(size_t)B_ * S_ + (size_t)b * S_ + t0] = make_float2(v1A, v1B);
      }
      if (tt == TT_ - 1 && low) {
        const int ph2 = s_h[0][hl >> 1];
        const half2_t h2v = __builtin_bit_cast(half2_t, ph2);
        out_hT[((size_t)2 * B_ + b) * H_ + hl] = (float)h2v[hl & 1];
        out_hT[((size_t)3 * B_ + b) * H_ + hl] = hB3;
        out_cT[((size_t)2 * B_ + b) * H_ + hl] = cc[0];
        out_cT[((size_t)3 * B_ + b) * H_ + hl] = cc[1];
      }
    }
  }
}

extern "C" void kernel_launch(void* const* d_in, const int* in_sizes, int n_in,
                              void* d_out, int out_size, void* d_ws, size_t ws_size,
                              hipStream_t stream) {
  (void)in_sizes; (void)n_in; (void)d_ws; (void)ws_size; (void)out_size;
  garch_dual_kernel<<<dim3(B_), dim3(128), 0, stream>>>(
      (const float*)d_in[0],  // obs_sequence [B,S,OBS]
      (const float*)d_in[1],  // prev_actions [B,S,NINS]
      (const float*)d_in[2],  // W_in [H, OBS+NINS]
      (const float*)d_in[3],  // b_in [H]
      (const float*)d_in[4],  // rms_w [NBLK,H]
      (const float*)d_in[5],  // W_ih [NBLK,4H,H]
      (const float*)d_in[6],  // W_hh [NBLK,4H,H]
      (const float*)d_in[7],  // b_ih [NBLK,4H]
      (const float*)d_in[8],  // b_hh [NBLK,4H]
      (const float*)d_in[9],  // head_w [NINS,H]
      (const float*)d_in[10], // head_b [NINS]
      (float*)d_out);
}